// Round 18
// baseline (494.217 us; speedup 1.0000x reference)
//
#include <hip/hip_runtime.h>

// Shapes
#define NB   256      // batch
#define E0   300      // embedding
#define EP   304      // padded K stride per j (304 = 38*8)
#define F_   512      // features
#define KP   1536     // padded K (5*304=1520 -> 48 ksubs of 32 / 12 ss of 128)
#define NKT  48
#define LQ_  64
#define LA_  256

typedef __attribute__((ext_vector_type(4))) float f32x4;
typedef __attribute__((ext_vector_type(8))) short short8;

#define WF_ELEMS (F_ * KP)               // 786,432 (16f-fragment-packed)
#define OUTQ_ELEMS ((size_t)NB * F_ * LQ_)

__device__ __forceinline__ unsigned short f2bf(float x) {
    unsigned int u = __float_as_uint(x);
    u = u + 0x7fffu + ((u >> 16) & 1u);   // RNE
    return (unsigned short)(u >> 16);
}

// Fragment-packed W (verified r5-r17): chunk (tile16, kc) = 1024B, lane holds
// f = tile16*16 + (lane&15), k' = kc*32 + (lane>>4)*8 + j-mapped via kp=j*304+e.
__global__ void prep_w2(const float* __restrict__ W, unsigned short* __restrict__ wfr)
{
    int idx = blockIdx.x * 256 + threadIdx.x;
    int j    = idx & 7;
    int lane = (idx >> 3) & 63;
    int chunk = idx >> 9;
    int kc = chunk % NKT;
    int tile16 = chunk / NKT;
    int f  = tile16 * 16 + (lane & 15);
    int kp = kc * 32 + (lane >> 4) * 8 + j;
    int jj = kp / EP;
    int e  = kp - jj * EP;
    float v = (kp < 5 * EP && e < E0) ? W[(size_t)(jj * E0 + e) * F_ + f] : 0.f;
    wfr[idx] = f2bf(v);
}

// r18 = r16 loop core (verified: 256f x 128l, 4 waves, acc[4][8], ring-2 64 KB,
// 2 blocks/CU, grid 1280, counted fences) with FUSED Z-STAGING: no prep_x pass.
// Z is read directly from the ORIGINAL fp32 q/a arrays, converted + halo-masked
// in-register, and ds_write'n into the byte-identical LDS layout the verified
// ds-reads use.  Key facts making this exact:
//  - L is a power of two in both regions -> region row id r == b*L + l.
//  - 304 % 8 == 0 -> each 16B bf16 chunk lies in ONE j-slice: kp = j*304 + e;
//    source floats = x[(r + j - 2)*300 + e .. +7].
//  - row validity: dj = j-2 clamped to [-l, L-1-l]; invalid -> addr clamped
//    in-batch (in-bounds) and VALUE masked to 0 (W nonzero there).
//  - e==296 chunk: its 2nd dwordx4 would touch [300..304) = next row (OOB only
//    at the array's last row) -> redirect to the 1st half's addr; those slots
//    have W==0 (don't-care).  e>=300 and kp>=1520 slots likewise W==0.
// Per-wave in-order VM ledger (Zh = 8 fp32 dwordx4 via asm, W4 = 4 loads):
//  entry [W8 (prev burst2)].  +Zh1(S+1) -> F1 vmcnt(8) lgkm(0) retires W8.
//  burst1 (ksub0 wA, ksub1 wB) + W4A + W4B -> [Zh1, W8].
//  F2 vmcnt(8) retires Zh1 -> cvt+mask+4x ds_write (half A rows).
//  +Zh2(S+1) -> [W8, Zh2]; ZRD blk2,3; F3 vmcnt(8) lgkm(0) retires W8
//  (lgkm drains 16 reads + 4 writes).  burst2 + W4A + W4B -> [Zh2, W8'].
//  F4 vmcnt(8) retires Zh2 -> cvt+write (half B); lgkm(0); s_barrier.
//  exit [W8'] = entry invariant.  Ring-2 WAR: writes for S+1 target the buf
//  last read in S-1, drained at S-1's F3 lgkm(0) before its end barrier.
//  Prologue: W4A,W4B,Zh1(0),Zh2(0) -> vmcnt(0); cvt+write both; lgkm(0); bar.
//  Tail S=11: no Z; F1/F3 vmcnt(0); burst1 loads k46/k47; burst2 loads none.
__global__ __launch_bounds__(256, 2) void qa_gemm(
    const float* __restrict__ xqf,
    const float* __restrict__ xaf,
    const unsigned short* __restrict__ wfr,
    const float* __restrict__ bias,
    float* __restrict__ out)
{
    __shared__ __align__(16) unsigned short lds[2 * 16384];   // 64 KB Z-ring

    const int bid = blockIdx.x;
    const int wg  = (bid & 7) * 160 + (bid >> 3);   // XCD swizzle, 1280 % 8 == 0

    const int ftBase = (wg & 1) * 256;
    const int lt     = wg >> 1;                     // 0..639, tile of 128 l-rows

    const float* X;
    float* ob;
    int Mb, lsh;
    if (lt < 128) { Mb = lt * 128;         X = xqf; lsh = 6; ob = out; }
    else          { Mb = (lt - 128) * 128; X = xaf; lsh = 8; ob = out + OUTQ_ELEMS; }
    const int Lv = 1 << lsh;                        // == L exactly (64 / 256)

    const int tid  = threadIdx.x;
    const int lane = tid & 63;
    const int wid  = tid >> 6;      // wave = 64f slice; all share the 128l tile
    const int lq   = lane >> 4;
    const int lr   = lane & 15;
    const int q4   = lane & 3;
    const int sub  = lane >> 2;
    const int c8   = (q4 ^ ((sub >> 1) & 3)) * 8;   // source chunk (verified swizzle)

    // staged rows (region-local; r == b*L + l since Lv == L)
    const int r0 = Mb + wid * 32 + sub, r1 = r0 + 16;
    const int l0 = r0 & (Lv - 1),       l1 = r1 & (Lv - 1);

    // ---- W fragment chains (verified layout); two sets, stride 2 kc per load
    const unsigned short* wpA0 = wfr + (size_t)((ftBase >> 4) + wid * 4 + 0) * NKT * 512 + lane * 8;
    const unsigned short* wpA1 = wfr + (size_t)((ftBase >> 4) + wid * 4 + 1) * NKT * 512 + lane * 8;
    const unsigned short* wpA2 = wfr + (size_t)((ftBase >> 4) + wid * 4 + 2) * NKT * 512 + lane * 8;
    const unsigned short* wpA3 = wfr + (size_t)((ftBase >> 4) + wid * 4 + 3) * NKT * 512 + lane * 8;
    const unsigned short* wpB0 = wpA0 + 512;
    const unsigned short* wpB1 = wpA1 + 512;
    const unsigned short* wpB2 = wpA2 + 512;
    const unsigned short* wpB3 = wpA3 + 512;

    // ---- Z fragment LDS read offsets (bytes; verified r8-r17 family)
    const int cs = (lq ^ ((lr >> 1) & 3)) * 16;
    int zoff[8];
#pragma unroll
    for (int n = 0; n < 8; ++n) zoff[n] = (n * 16 + lr) * 64 + cs;

#define WLOAD(dst, p) do {                                                           \
    asm volatile("global_load_dwordx4 %0, %1, off" : "=v"(dst) : "v"(p) : "memory"); \
    (p) += 1024; } while (0)
#define W4A do { WLOAD(wA[0], wpA0); WLOAD(wA[1], wpA1);                             \
                 WLOAD(wA[2], wpA2); WLOAD(wA[3], wpA3); } while (0)
#define W4B do { WLOAD(wB[0], wpB0); WLOAD(wB[1], wpB1);                             \
                 WLOAD(wB[2], wpB2); WLOAD(wB[3], wpB3); } while (0)

// Issue 8 async fp32 loads for one 16-row half of tile T (4 ksub-blocks).
#define ZISSUE(RL, LL, T, FR, VL) do {                                               \
    _Pragma("unroll") for (int kb = 0; kb < 4; ++kb) {                               \
        const int kp = (T) * 128 + kb * 32 + c8;                                     \
        const int j  = kp / 304;                                                     \
        const int e  = kp - j * 304;                                                 \
        const int dj = j - 2;                                                        \
        const int lo = -(LL), hi = (Lv - 1) - (LL);                                  \
        const int djc = dj < lo ? lo : (dj > hi ? hi : dj);                          \
        VL[kb] = (dj == djc);                                                        \
        const float* a1 = X + (size_t)((RL) + djc) * 300 + e;                        \
        const float* a2 = (e == 296) ? a1 : a1 + 4;                                  \
        asm volatile("global_load_dwordx4 %0, %1, off" : "=v"(FR[kb][0]) : "v"(a1) : "memory"); \
        asm volatile("global_load_dwordx4 %0, %1, off" : "=v"(FR[kb][1]) : "v"(a2) : "memory"); \
    } } while (0)

// Convert + halo-mask + ds_write one half (H=0: rows r0 block, H=1: r1 block).
#define CVTW(FR, VL, H, T) do {                                                      \
    const int rbB = (((T) & 1) * 32768) + wid * 2048 + (H) * 1024 + lane * 16;       \
    _Pragma("unroll") for (int kb = 0; kb < 4; ++kb) {                               \
        unsigned int u0 = (unsigned)f2bf(FR[kb][0].x) | ((unsigned)f2bf(FR[kb][0].y) << 16); \
        unsigned int u1 = (unsigned)f2bf(FR[kb][0].z) | ((unsigned)f2bf(FR[kb][0].w) << 16); \
        unsigned int u2 = (unsigned)f2bf(FR[kb][1].x) | ((unsigned)f2bf(FR[kb][1].y) << 16); \
        unsigned int u3 = (unsigned)f2bf(FR[kb][1].z) | ((unsigned)f2bf(FR[kb][1].w) << 16); \
        uint4 uu;                                                                    \
        uu.x = VL[kb] ? u0 : 0u; uu.y = VL[kb] ? u1 : 0u;                            \
        uu.z = VL[kb] ? u2 : 0u; uu.w = VL[kb] ? u3 : 0u;                            \
        *(uint4*)((char*)lds + rbB + kb * 8192) = uu;                                \
    } } while (0)

#define ZRD8(DST, BLK) do { _Pragma("unroll") for (int n = 0; n < 8; ++n)            \
    DST[n] = *(const short8*)(bbase + (BLK) * 8192 + zoff[n]); } while (0)
#define SB __builtin_amdgcn_sched_barrier(0)
#define FENCE(VM, LG) do {                                                           \
    asm volatile("s_waitcnt vmcnt(" #VM ") lgkmcnt(" #LG ")" ::: "memory"); SB; } while (0)
#define FENCEV(VM) do {                                                              \
    asm volatile("s_waitcnt vmcnt(" #VM ")" ::: "memory"); SB; } while (0)
#define MFMA32K(WU, ZU) do { __builtin_amdgcn_s_setprio(1);                          \
    _Pragma("unroll") for (int mf = 0; mf < 4; ++mf)                                 \
    _Pragma("unroll") for (int nt = 0; nt < 8; ++nt)                                 \
        acc[mf][nt] = __builtin_amdgcn_mfma_f32_16x16x32_bf16(                       \
            WU[mf], ZU[nt], acc[mf][nt], 0, 0, 0);                                   \
    __builtin_amdgcn_s_setprio(0); SB; } while (0)

    f32x4 acc[4][8] = {};
    short8 zA[8], zB[8], wA[4], wB[4];
    float4 zf1[4][2], zf2[4][2];
    int vl1[4], vl2[4];

    // Prologue: W(k0),W(k1); stage tile 0 (both halves); drain; convert; publish.
    W4A; W4B;
    ZISSUE(r0, l0, 0, zf1, vl1);
    ZISSUE(r1, l1, 0, zf2, vl2);
    FENCE(0, 0);
    CVTW(zf1, vl1, 0, 0);
    CVTW(zf2, vl2, 1, 0);
    asm volatile("s_waitcnt lgkmcnt(0)\n\ts_barrier" ::: "memory");

    for (int S = 0; S < 11; ++S) {
        const char* bbase = (const char*)lds + (S & 1) * 32768;
        ZISSUE(r0, l0, S + 1, zf1, vl1);
        ZRD8(zA, 0); ZRD8(zB, 1);
        FENCE(8, 0);                        // retire prev W8; Zh1 in flight
        MFMA32K(wA, zA); W4A;
        MFMA32K(wB, zB); W4B;
        FENCEV(8);                          // retire Zh1 (oldest)
        CVTW(zf1, vl1, 0, S + 1);
        ZISSUE(r1, l1, S + 1, zf2, vl2);
        ZRD8(zA, 2); ZRD8(zB, 3);
        FENCE(8, 0);                        // retire burst1 W8; drain reads+writes
        MFMA32K(wA, zA); W4A;
        MFMA32K(wB, zB); W4B;
        FENCEV(8);                          // retire Zh2
        CVTW(zf2, vl2, 1, S + 1);
        asm volatile("s_waitcnt lgkmcnt(0)\n\ts_barrier" ::: "memory");
    }
    {   // S = 11: no staging; burst1 loads k46/k47; burst2 loads nothing
        const char* bbase = (const char*)lds + 32768;
        ZRD8(zA, 0); ZRD8(zB, 1);
        FENCE(0, 0);
        MFMA32K(wA, zA); W4A;
        MFMA32K(wB, zB); W4B;
        ZRD8(zA, 2); ZRD8(zB, 3);
        FENCE(0, 0);
        MFMA32K(wA, zA);
        MFMA32K(wB, zB);
    }

#undef MFMA32K
#undef FENCEV
#undef FENCE
#undef SB
#undef ZRD8
#undef CVTW
#undef ZISSUE
#undef W4A
#undef W4B
#undef WLOAD

    // ---- epilogue: D row = f = lq*4+reg, col = l = lr (verified r1-r17)
#pragma unroll
    for (int nt = 0; nt < 8; ++nt) {
        const int m = Mb + nt * 16 + lr;
        const int b = m >> lsh;
        const int l = m & (Lv - 1);
        float* orow = ob + ((size_t)b * F_ << lsh) + l;
#pragma unroll
        for (int mf = 0; mf < 4; ++mf) {
            const int f0 = ftBase + wid * 64 + mf * 16 + lq * 4;
            const f32x4 v = acc[mf][nt];
#pragma unroll
            for (int r = 0; r < 4; ++r)
                orow[(size_t)(f0 + r) << lsh] = v[r] + __ldg(&bias[f0 + r]);
        }
    }
}

extern "C" void kernel_launch(void* const* d_in, const int* in_sizes, int n_in,
                              void* d_out, int out_size, void* d_ws, size_t ws_size,
                              hipStream_t stream)
{
    const float* q    = (const float*)d_in[0];
    const float* a    = (const float*)d_in[1];
    const float* W    = (const float*)d_in[2];
    const float* bias = (const float*)d_in[3];
    float* out = (float*)d_out;

    unsigned short* wfr = (unsigned short*)d_ws;   // 1.5 MB only

    prep_w2<<<WF_ELEMS / 256, 256, 0, stream>>>(W, wfr);
    qa_gemm<<<1280, 256, 0, stream>>>(q, a, wfr, bias, out);
}